// Round 1
// baseline (32783.759 us; speedup 1.0000x reference)
//
#include <hip/hip_runtime.h>
#include <math.h>

#define NBLK 96
#define BLK  256
#define NSTATE 3072
#define HID  768

// Tsit5 coefficients
#define C_A21 0.161f
#define C_A31 (-0.008480655492356989f)
#define C_A32 0.335480655492357f
#define C_A41 2.8971530571054935f
#define C_A42 (-6.359448489975075f)
#define C_A43 4.3622954328695815f
#define C_A51 5.325864828439257f
#define C_A52 (-11.748883564062828f)
#define C_A53 7.4955393428898365f
#define C_A54 (-0.09249506636175525f)
#define C_A61 5.86145544294642f
#define C_A62 (-12.92096931784711f)
#define C_A63 8.159367898576159f
#define C_A64 (-0.071584973281401f)
#define C_A65 (-0.028269050394068383f)
#define C_B1 0.09646076681806523f
#define C_B2 0.01f
#define C_B3 0.4798896504144996f
#define C_B4 1.379008574103742f
#define C_B5 (-3.290069515436081f)
#define C_B6 2.324710524099774f
#define C_E1 (-0.001780011052226f)
#define C_E2 (-0.000816434459657f)
#define C_E3 0.007880878010262f
#define C_E4 (-0.144711007173263f)
#define C_E5 0.582357165452555f
#define C_E6 (-0.458082105929187f)
#define C_E7 0.015151515151515152f

__constant__ float A_TAB[7][6] = {
  {0.f,0.f,0.f,0.f,0.f,0.f},
  {C_A21,0.f,0.f,0.f,0.f,0.f},
  {C_A31,C_A32,0.f,0.f,0.f,0.f},
  {C_A41,C_A42,C_A43,0.f,0.f,0.f},
  {C_A51,C_A52,C_A53,C_A54,0.f,0.f},
  {C_A61,C_A62,C_A63,C_A64,C_A65,0.f},
  {C_B1,C_B2,C_B3,C_B4,C_B5,C_B6},
};

// persistent global scratch (avoids d_ws sizing assumptions)
__device__ __align__(16) float g_yA[NSTATE];
__device__ __align__(16) float g_yB[NSTATE];
__device__ __align__(16) float g_k[7][NSTATE];
__device__ __align__(16) float g_hA[HID];
__device__ __align__(16) float g_hB[HID];
__device__ float g_part[NBLK];
__device__ unsigned g_arrive;

__global__ void reset_kernel(){ g_arrive = 0u; }

__device__ __forceinline__ float softplus_f(float x){
  // jax.nn.softplus = logaddexp(x, 0) = max(x,0) + log1p(exp(-|x|))
  return fmaxf(x, 0.0f) + log1pf(expf(-fabsf(x)));
}

// monotonic-counter grid barrier; all NBLK blocks must be co-resident (96 <= 256 CUs).
// On timeout, poison the counter so every block exits fast (fail visibly, no hang).
__device__ __forceinline__ void gsync(unsigned& epoch){
  __syncthreads();
  if (threadIdx.x == 0){
    __hip_atomic_fetch_add(&g_arrive, 1u, __ATOMIC_RELEASE, __HIP_MEMORY_SCOPE_AGENT);
    const unsigned tgt = epoch + (unsigned)NBLK;
    unsigned guard = 0;
    while (__hip_atomic_load(&g_arrive, __ATOMIC_ACQUIRE, __HIP_MEMORY_SCOPE_AGENT) < tgt){
      __builtin_amdgcn_s_sleep(2);
      if (++guard > (1u<<22)){
        __hip_atomic_fetch_add(&g_arrive, 1u<<24, __ATOMIC_RELEASE, __HIP_MEMORY_SCOPE_AGENT);
        break;
      }
    }
  }
  epoch += (unsigned)NBLK;
  __syncthreads();
}

struct Params {
  const float* Win; const float* bin;
  const float* Whid; const float* bhid;
  const float* Wout; const float* bout;
};

// One f-eval: z = y + dte * sum_j A[st][j]*k_{j+1}  (st=0: z=y; st=6: z=y1, also store y1)
// then 5-layer MLP, output written to k-slot for this stage. 5 grid syncs.
__device__ void feval(int st, float dte, int cur, int kpar, const Params& p,
                      float* zs, float* hs, unsigned& epoch)
{
  const int tid = threadIdx.x;
  const int blk = blockIdx.x;
  const float* ycur  = cur ? g_yB : g_yA;
  float*       ynext = cur ? g_yA : g_yB;
  const float* k1p = kpar ? g_k[6] : g_k[0];

  // ---- build z (full 3072) into LDS; stage 6 also writes this block's y1 slice ----
  {
    const float4* yc4 = reinterpret_cast<const float4*>(ycur);
    const float4* k14 = reinterpret_cast<const float4*>(k1p);
    float4* yn4 = reinterpret_cast<float4*>(ynext);
    float4* z4  = reinterpret_cast<float4*>(zs);
    for (int i = tid; i < NSTATE/4; i += BLK){
      float4 yv = yc4[i];
      float sx=0.f, sy=0.f, sz=0.f, sw=0.f;
      if (st > 0){
        {
          float c = A_TAB[st][0];
          float4 kv = k14[i];
          sx = c*kv.x; sy = c*kv.y; sz = c*kv.z; sw = c*kv.w;
        }
        for (int j = 1; j < st; ++j){
          float c = A_TAB[st][j];
          float4 kv = reinterpret_cast<const float4*>(g_k[j])[i];
          sx += c*kv.x; sy += c*kv.y; sz += c*kv.z; sw += c*kv.w;
        }
      }
      float4 zv;
      zv.x = yv.x + dte*sx; zv.y = yv.y + dte*sy;
      zv.z = yv.z + dte*sz; zv.w = yv.w + dte*sw;
      z4[i] = zv;
      if (st == 6 && ((i >> 3) == blk)) yn4[i] = zv;   // i>>3 == (i*4)>>5
    }
  }
  __syncthreads();

  // ---- layer 1: [768 x 3072], 8 rows/block, 32 lanes/row ----
  {
    const int row  = blk*8 + (tid >> 5);
    const int lane = tid & 31;
    const float* wr = p.Win + (size_t)row * NSTATE;
    float acc = 0.f;
    for (int j = lane*4; j < NSTATE; j += 128){
      float4 w  = *reinterpret_cast<const float4*>(wr + j);
      float4 zz = *reinterpret_cast<const float4*>(zs + j);
      acc += w.x*zz.x + w.y*zz.y + w.z*zz.z + w.w*zz.w;
    }
    acc += __shfl_xor(acc,16); acc += __shfl_xor(acc,8);
    acc += __shfl_xor(acc,4);  acc += __shfl_xor(acc,2);
    acc += __shfl_xor(acc,1);
    if (lane == 0) g_hA[row] = softplus_f(acc + p.bin[row]);
  }
  gsync(epoch);

  // ---- 3 hidden layers: [768 x 768] ----
  for (int l = 0; l < 3; ++l){
    const float* hin  = (l & 1) ? g_hB : g_hA;
    float*       hout = (l & 1) ? g_hA : g_hB;
    for (int e = tid; e < HID; e += BLK) hs[e] = hin[e];
    __syncthreads();
    const int row  = blk*8 + (tid >> 5);
    const int lane = tid & 31;
    const float* wr = p.Whid + ((size_t)l*HID + row) * HID;
    float acc = 0.f;
    for (int j = lane*4; j < HID; j += 128){
      float4 w  = *reinterpret_cast<const float4*>(wr + j);
      float4 hh = *reinterpret_cast<const float4*>(hs + j);
      acc += w.x*hh.x + w.y*hh.y + w.z*hh.z + w.w*hh.w;
    }
    acc += __shfl_xor(acc,16); acc += __shfl_xor(acc,8);
    acc += __shfl_xor(acc,4);  acc += __shfl_xor(acc,2);
    acc += __shfl_xor(acc,1);
    if (lane == 0) hout[row] = softplus_f(acc + p.bhid[l*HID + row]);
    gsync(epoch);
  }

  // ---- output layer: [3072 x 768], h4 lives in g_hB; 32 rows/block, 8 lanes/row ----
  for (int e = tid; e < HID; e += BLK) hs[e] = g_hB[e];
  __syncthreads();
  {
    const int row = blk*32 + (tid >> 3);
    const int l8  = tid & 7;
    const float* wr = p.Wout + (size_t)row * HID;
    float acc = 0.f;
    for (int j = l8*4; j < HID; j += 32){
      float4 w  = *reinterpret_cast<const float4*>(wr + j);
      float4 hh = *reinterpret_cast<const float4*>(hs + j);
      acc += w.x*hh.x + w.y*hh.y + w.z*hh.z + w.w*hh.w;
    }
    acc += __shfl_xor(acc,4); acc += __shfl_xor(acc,2); acc += __shfl_xor(acc,1);
    const int slot = (st == 0) ? (kpar ? 6 : 0)
                   : ((st == 6) ? (kpar ? 0 : 6) : st);
    if (l8 == 0) g_k[slot][row] = acc + p.bout[row];
  }
  gsync(epoch);
}

__global__ __launch_bounds__(BLK)
void ode_kernel(const float* __restrict__ y0,
                const float* __restrict__ Win,  const float* __restrict__ bin,
                const float* __restrict__ Whid, const float* __restrict__ bhid,
                const float* __restrict__ Wout, const float* __restrict__ bout,
                const float* __restrict__ eps,  float* __restrict__ out)
{
  __shared__ float zs[NSTATE];
  __shared__ float hs[HID];
  __shared__ float s_err;
  const int tid = threadIdx.x;
  const int blk = blockIdx.x;
  unsigned epoch = 0;
  Params p{Win,bin,Whid,bhid,Wout,bout};

  // init y (partitioned) and output row 0
  if (tid < 32){ int e = blk*32 + tid; g_yA[e] = y0[e]; }
  if (tid < 8){ int e = blk*8 + tid; out[e] = y0[e] + eps[e]*y0[HID + e]; }
  gsync(epoch);

  float t = 0.f, dtv = 0.1f;   // DT0
  int cur = 0, kpar = 0;

  // k1 = f(y0): computed exactly once; thereafter k1 is FSAL-carried
  feval(0, 0.f, cur, kpar, p, zs, hs, epoch);

  for (int iv = 1; iv < 100; ++iv){
    const float t1 = (float)iv / 99.0f;
    for (int a = 0; a < 6; ++a){
      if (t >= t1 - 1e-10f) break;           // 'done' => remaining attempts are no-ops
      const float dte = fminf(dtv, t1 - t);

      for (int st = 1; st <= 6; ++st)
        feval(st, dte, cur, kpar, p, zs, hs, epoch);

      // error norm: per-block partial over its 32-elem slice, then deterministic sum
      {
        const float* k1p   = kpar ? g_k[6] : g_k[0];
        const float* k7p   = kpar ? g_k[0] : g_k[6];
        const float* ycur  = cur ? g_yB : g_yA;
        const float* ynext = cur ? g_yA : g_yB;
        if (tid < 32){
          int e = blk*32 + tid;
          float ev = C_E1*k1p[e] + C_E2*g_k[1][e] + C_E3*g_k[2][e]
                   + C_E4*g_k[3][e] + C_E5*g_k[4][e] + C_E6*g_k[5][e]
                   + C_E7*k7p[e];
          ev *= dte;
          float sc = 1e-6f + 1e-3f * fmaxf(fabsf(ycur[e]), fabsf(ynext[e]));
          float q = ev / sc;
          float v = q*q;
          v += __shfl_xor(v,16); v += __shfl_xor(v,8); v += __shfl_xor(v,4);
          v += __shfl_xor(v,2);  v += __shfl_xor(v,1);
          if (tid == 0) g_part[blk] = v;
        }
      }
      gsync(epoch);
      if (tid == 0){
        float s = 0.f;
        for (int b = 0; b < NBLK; ++b) s += g_part[b];   // fixed order => identical on all blocks
        s_err = sqrtf(s * (1.0f/3072.0f));
      }
      __syncthreads();
      const float err = s_err;
      __syncthreads();

      const bool accept = (err <= 1.0f);
      const float factor = fminf(fmaxf(0.9f * powf(fmaxf(err, 1e-10f), -0.2f), 0.2f), 10.0f);
      if (accept){ t = t + dte; cur ^= 1; kpar ^= 1; }  // y <- y1, k1 <- k7 (buffer swap)
      dtv = dte * factor;
    }
    t = t1;
    // emit output row iv from current y
    if (tid < 8){
      const float* yc = cur ? g_yB : g_yA;
      int e = blk*8 + tid;
      out[(size_t)iv*HID + e] = yc[e] + eps[(size_t)iv*HID + e]*yc[HID + e];
    }
  }
}

extern "C" void kernel_launch(void* const* d_in, const int* in_sizes, int n_in,
                              void* d_out, int out_size, void* d_ws, size_t ws_size,
                              hipStream_t stream) {
  const float* y0   = (const float*)d_in[0];
  const float* Win  = (const float*)d_in[1];
  const float* bin  = (const float*)d_in[2];
  const float* Whid = (const float*)d_in[3];
  const float* bhid = (const float*)d_in[4];
  const float* Wout = (const float*)d_in[5];
  const float* bout = (const float*)d_in[6];
  const float* eps  = (const float*)d_in[7];
  float* out = (float*)d_out;
  (void)in_sizes; (void)n_in; (void)out_size; (void)d_ws; (void)ws_size;

  reset_kernel<<<dim3(1), dim3(1), 0, stream>>>();
  ode_kernel<<<dim3(NBLK), dim3(BLK), 0, stream>>>(y0, Win, bin, Whid, bhid, Wout, bout, eps, out);
}

// Round 2
// 23274.557 us; speedup vs baseline: 1.4086x; 1.4086x over previous
//
#include <hip/hip_runtime.h>
#include <math.h>

#define NBLK 192
#define BLK  256
#define NSTATE 3072
#define HID  768

namespace {
constexpr float AT[7][6] = {
  {0.f,0.f,0.f,0.f,0.f,0.f},
  {0.161f,0.f,0.f,0.f,0.f,0.f},
  {-0.008480655492356989f,0.335480655492357f,0.f,0.f,0.f,0.f},
  {2.8971530571054935f,-6.359448489975075f,4.3622954328695815f,0.f,0.f,0.f},
  {5.325864828439257f,-11.748883564062828f,7.4955393428898365f,-0.09249506636175525f,0.f,0.f},
  {5.86145544294642f,-12.92096931784711f,8.159367898576159f,-0.071584973281401f,-0.028269050394068383f,0.f},
  {0.09646076681806523f,0.01f,0.4798896504144996f,1.379008574103742f,-3.290069515436081f,2.324710524099774f},
};
constexpr float EC1=-0.001780011052226f, EC2=-0.000816434459657f, EC3=0.007880878010262f,
                EC4=-0.144711007173263f, EC5=0.582357165452555f, EC6=-0.458082105929187f,
                EC7=0.015151515151515152f;
template<int N> struct IC { static constexpr int value = N; };
}

// one 128B cacheline per block: arrive stores never serialize on a shared line
struct alignas(128) ASlot { unsigned v; unsigned pad[31]; };
__device__ ASlot g_arr[NBLK];
__device__ __align__(16) float g_yA[NSTATE];
__device__ __align__(16) float g_yB[NSTATE];
__device__ __align__(16) float g_k[7][NSTATE];
__device__ __align__(16) float g_hA[HID];
__device__ __align__(16) float g_hB[HID];

__global__ void reset_kernel(){ if (threadIdx.x < NBLK) g_arr[threadIdx.x].v = 0u; }

__device__ __forceinline__ float softplus_f(float x){
  // jax.nn.softplus = max(x,0) + log1p(exp(-|x|))
  return fmaxf(x, 0.0f) + log1pf(expf(-fabsf(x)));
}

// Flat all-poll-all barrier: per-block arrive slot (release store, own cacheline),
// threads 0..NBLK-1 of EVERY block poll the slots in parallel (relaxed), then one
// acquire load per block for visibility. One fabric hop, no RMW serialization.
__device__ __forceinline__ void gsync(unsigned& epoch){
  const unsigned e = epoch + 1u;
  __syncthreads();
  if (threadIdx.x == 0)
    __hip_atomic_store(&g_arr[blockIdx.x].v, e, __ATOMIC_RELEASE, __HIP_MEMORY_SCOPE_AGENT);
  if (threadIdx.x < NBLK){
    unsigned guard = 0;
    while (__hip_atomic_load(&g_arr[threadIdx.x].v, __ATOMIC_RELAXED, __HIP_MEMORY_SCOPE_AGENT) < e){
      __builtin_amdgcn_s_sleep(2);
      if (++guard > (1u<<22)) break;   // bail visibly instead of hanging
    }
  }
  __syncthreads();
  if (threadIdx.x == 0){
    unsigned tmp = __hip_atomic_load(&g_arr[blockIdx.x].v, __ATOMIC_ACQUIRE, __HIP_MEMORY_SCOPE_AGENT);
    asm volatile("" :: "v"(tmp));      // keep the acquire load alive
  }
  __syncthreads();
  epoch = e;
}

__global__ __launch_bounds__(BLK)
void ode_kernel(const float* __restrict__ y0,
                const float* __restrict__ Win,  const float* __restrict__ bin,
                const float* __restrict__ Whid, const float* __restrict__ bhid,
                const float* __restrict__ Wout, const float* __restrict__ bout,
                const float* __restrict__ eps,  float* __restrict__ out)
{
  __shared__ float zs[NSTATE];
  __shared__ float red[4];
  const int tid  = threadIdx.x, blk = blockIdx.x;
  const int wave = tid >> 6, lane = tid & 63;
  const int row1 = blk*4 + wave;                       // layer1 + hidden row (1 wave per row)
  const int rowo = blk*16 + wave*4 + (lane >> 4);      // out row (16 lanes per row)
  const int l16  = lane & 15;
  unsigned epoch = 0;

  // fixed per-thread weight bases + bias registers (rows never change)
  const float4* w1  = reinterpret_cast<const float4*>(Win  + (size_t)row1*NSTATE) + lane;
  const float4* wh0 = reinterpret_cast<const float4*>(Whid + ((size_t)0*HID + row1)*HID) + lane;
  const float4* wh1 = reinterpret_cast<const float4*>(Whid + ((size_t)1*HID + row1)*HID) + lane;
  const float4* wh2 = reinterpret_cast<const float4*>(Whid + ((size_t)2*HID + row1)*HID) + lane;
  const float4* wo  = reinterpret_cast<const float4*>(Wout + (size_t)rowo*HID) + l16;
  const float b1  = bin[row1];
  const float bhv0 = bhid[row1], bhv1 = bhid[HID+row1], bhv2 = bhid[2*HID+row1];
  const float bo  = bout[rowo];

  // init y and output row 0
  if (tid < 16){ const int e2 = blk*16 + tid; g_yA[e2] = y0[e2]; }
  if (tid < 4){  const int e2 = blk*4 + tid;  out[e2] = y0[e2] + eps[e2]*y0[HID+e2]; }
  gsync(epoch);

  int cur = 0, kpar = 0;

  auto feval = [&](auto stc, float dte){
    constexpr int ST = decltype(stc)::value;
    const float* ycur = cur ? g_yB : g_yA;
    float*       ynxt = cur ? g_yA : g_yB;
    const float4* yc4 = reinterpret_cast<const float4*>(ycur);
    const float4* k14 = reinterpret_cast<const float4*>(kpar ? g_k[6] : g_k[0]);
    float4* z4 = reinterpret_cast<float4*>(zs);

    // ---- build z into LDS (each block redundantly, 3 f4/thread); ST==6 also stores y1 slice ----
    #pragma unroll
    for (int g2 = 0; g2 < 3; ++g2){
      const int i = tid + BLK*g2;
      float4 yv = yc4[i];
      float sx=0.f, sy=0.f, sz=0.f, sw=0.f;
      if constexpr (ST >= 1){
        float4 kv = k14[i];
        sx = AT[ST][0]*kv.x; sy = AT[ST][0]*kv.y; sz = AT[ST][0]*kv.z; sw = AT[ST][0]*kv.w;
        #pragma unroll
        for (int j = 1; j < ST; ++j){
          float4 k2v = reinterpret_cast<const float4*>(g_k[j])[i];
          sx += AT[ST][j]*k2v.x; sy += AT[ST][j]*k2v.y;
          sz += AT[ST][j]*k2v.z; sw += AT[ST][j]*k2v.w;
        }
      }
      float4 zv; zv.x = yv.x + dte*sx; zv.y = yv.y + dte*sy;
                 zv.z = yv.z + dte*sz; zv.w = yv.w + dte*sw;
      z4[i] = zv;
      if constexpr (ST == 6){ if ((i >> 2) == blk) reinterpret_cast<float4*>(ynxt)[i] = zv; }
    }
    __syncthreads();

    // ---- layer 1: 768x3072, 1 wave per row, 12 f4 per lane ----
    {
      const float4* zl = z4 + lane;
      float acc = 0.f;
      #pragma unroll
      for (int i2 = 0; i2 < 12; ++i2){
        float4 w = w1[64*i2]; float4 x = zl[64*i2];
        acc = fmaf(w.x,x.x, fmaf(w.y,x.y, fmaf(w.z,x.z, fmaf(w.w,x.w, acc))));
      }
      acc += __shfl_xor(acc,32); acc += __shfl_xor(acc,16); acc += __shfl_xor(acc,8);
      acc += __shfl_xor(acc,4);  acc += __shfl_xor(acc,2);  acc += __shfl_xor(acc,1);
      if (lane == 0) g_hA[row1] = softplus_f(acc + b1);
    }
    gsync(epoch);

    // ---- hidden 0: g_hA -> g_hB ----
    {
      const float4* hx = reinterpret_cast<const float4*>(g_hA) + lane;
      float acc = 0.f;
      #pragma unroll
      for (int i2 = 0; i2 < 3; ++i2){
        float4 w = wh0[64*i2]; float4 x = hx[64*i2];
        acc = fmaf(w.x,x.x, fmaf(w.y,x.y, fmaf(w.z,x.z, fmaf(w.w,x.w, acc))));
      }
      acc += __shfl_xor(acc,32); acc += __shfl_xor(acc,16); acc += __shfl_xor(acc,8);
      acc += __shfl_xor(acc,4);  acc += __shfl_xor(acc,2);  acc += __shfl_xor(acc,1);
      if (lane == 0) g_hB[row1] = softplus_f(acc + bhv0);
    }
    gsync(epoch);

    // ---- hidden 1: g_hB -> g_hA ----
    {
      const float4* hx = reinterpret_cast<const float4*>(g_hB) + lane;
      float acc = 0.f;
      #pragma unroll
      for (int i2 = 0; i2 < 3; ++i2){
        float4 w = wh1[64*i2]; float4 x = hx[64*i2];
        acc = fmaf(w.x,x.x, fmaf(w.y,x.y, fmaf(w.z,x.z, fmaf(w.w,x.w, acc))));
      }
      acc += __shfl_xor(acc,32); acc += __shfl_xor(acc,16); acc += __shfl_xor(acc,8);
      acc += __shfl_xor(acc,4);  acc += __shfl_xor(acc,2);  acc += __shfl_xor(acc,1);
      if (lane == 0) g_hA[row1] = softplus_f(acc + bhv1);
    }
    gsync(epoch);

    // ---- hidden 2: g_hA -> g_hB ----
    {
      const float4* hx = reinterpret_cast<const float4*>(g_hA) + lane;
      float acc = 0.f;
      #pragma unroll
      for (int i2 = 0; i2 < 3; ++i2){
        float4 w = wh2[64*i2]; float4 x = hx[64*i2];
        acc = fmaf(w.x,x.x, fmaf(w.y,x.y, fmaf(w.z,x.z, fmaf(w.w,x.w, acc))));
      }
      acc += __shfl_xor(acc,32); acc += __shfl_xor(acc,16); acc += __shfl_xor(acc,8);
      acc += __shfl_xor(acc,4);  acc += __shfl_xor(acc,2);  acc += __shfl_xor(acc,1);
      if (lane == 0) g_hB[row1] = softplus_f(acc + bhv2);
    }
    gsync(epoch);

    // ---- out layer: 3072x768 from g_hB, 16 lanes per row, 12 f4 per lane ----
    {
      const float4* hx = reinterpret_cast<const float4*>(g_hB) + l16;
      float acc = 0.f;
      #pragma unroll
      for (int i2 = 0; i2 < 12; ++i2){
        float4 w = wo[16*i2]; float4 x = hx[16*i2];
        acc = fmaf(w.x,x.x, fmaf(w.y,x.y, fmaf(w.z,x.z, fmaf(w.w,x.w, acc))));
      }
      acc += __shfl_xor(acc,8); acc += __shfl_xor(acc,4);
      acc += __shfl_xor(acc,2); acc += __shfl_xor(acc,1);
      float* kdst = (ST == 0) ? (kpar ? g_k[6] : g_k[0])
                  : (ST == 6) ? (kpar ? g_k[0] : g_k[6])
                  : g_k[ST];
      if (l16 == 0) kdst[rowo] = acc + bo;
    }
    gsync(epoch);
  };

  // k1 = f(y0), computed once; FSAL-carried thereafter
  feval(IC<0>{}, 0.f);

  float t = 0.f, dtv = 0.1f;
  for (int iv = 1; iv < 100; ++iv){
    const float t1 = (float)iv / 99.0f;
    for (int a = 0; a < 6; ++a){
      if (t >= t1 - 1e-10f) break;                 // reference's masked no-op attempts
      const float dte = fminf(dtv, t1 - t);

      feval(IC<1>{}, dte); feval(IC<2>{}, dte); feval(IC<3>{}, dte);
      feval(IC<4>{}, dte); feval(IC<5>{}, dte); feval(IC<6>{}, dte);

      // ---- error norm: every block computes the FULL deterministic sum locally (no gsync) ----
      const float4* k1p = reinterpret_cast<const float4*>(kpar ? g_k[6] : g_k[0]);
      const float4* k7p = reinterpret_cast<const float4*>(kpar ? g_k[0] : g_k[6]);
      const float4* yc4 = reinterpret_cast<const float4*>(cur ? g_yB : g_yA);
      const float4* y14 = reinterpret_cast<const float4*>(cur ? g_yA : g_yB);
      float vsum = 0.f;
      #pragma unroll
      for (int g2 = 0; g2 < 3; ++g2){
        const int i = tid + BLK*g2;
        float4 a1=k1p[i];
        float4 a2=reinterpret_cast<const float4*>(g_k[1])[i];
        float4 a3=reinterpret_cast<const float4*>(g_k[2])[i];
        float4 a4=reinterpret_cast<const float4*>(g_k[3])[i];
        float4 a5=reinterpret_cast<const float4*>(g_k[4])[i];
        float4 a6=reinterpret_cast<const float4*>(g_k[5])[i];
        float4 a7=k7p[i];
        float4 yv=yc4[i], y1=y14[i];
        {
          float ev = dte*(EC1*a1.x+EC2*a2.x+EC3*a3.x+EC4*a4.x+EC5*a5.x+EC6*a6.x+EC7*a7.x);
          float sc = 1e-6f + 1e-3f*fmaxf(fabsf(yv.x), fabsf(y1.x));
          float q = ev/sc; vsum += q*q;
        }
        {
          float ev = dte*(EC1*a1.y+EC2*a2.y+EC3*a3.y+EC4*a4.y+EC5*a5.y+EC6*a6.y+EC7*a7.y);
          float sc = 1e-6f + 1e-3f*fmaxf(fabsf(yv.y), fabsf(y1.y));
          float q = ev/sc; vsum += q*q;
        }
        {
          float ev = dte*(EC1*a1.z+EC2*a2.z+EC3*a3.z+EC4*a4.z+EC5*a5.z+EC6*a6.z+EC7*a7.z);
          float sc = 1e-6f + 1e-3f*fmaxf(fabsf(yv.z), fabsf(y1.z));
          float q = ev/sc; vsum += q*q;
        }
        {
          float ev = dte*(EC1*a1.w+EC2*a2.w+EC3*a3.w+EC4*a4.w+EC5*a5.w+EC6*a6.w+EC7*a7.w);
          float sc = 1e-6f + 1e-3f*fmaxf(fabsf(yv.w), fabsf(y1.w));
          float q = ev/sc; vsum += q*q;
        }
      }
      vsum += __shfl_xor(vsum,32); vsum += __shfl_xor(vsum,16); vsum += __shfl_xor(vsum,8);
      vsum += __shfl_xor(vsum,4);  vsum += __shfl_xor(vsum,2);  vsum += __shfl_xor(vsum,1);
      if (lane == 0) red[wave] = vsum;
      __syncthreads();
      const float err = sqrtf((red[0]+red[1]+red[2]+red[3]) * (1.0f/3072.0f));
      __syncthreads();

      const bool accept = (err <= 1.0f);
      const float factor = fminf(fmaxf(0.9f * powf(fmaxf(err, 1e-10f), -0.2f), 0.2f), 10.0f);
      if (accept){ t += dte; cur ^= 1; kpar ^= 1; }  // y <- y1, k1 <- k7
      dtv = dte * factor;
    }
    t = t1;
    if (tid < 4){
      const float* yc = cur ? g_yB : g_yA;
      const int e2 = blk*4 + tid;
      out[(size_t)iv*HID + e2] = yc[e2] + eps[(size_t)iv*HID + e2]*yc[HID+e2];
    }
  }
}

extern "C" void kernel_launch(void* const* d_in, const int* in_sizes, int n_in,
                              void* d_out, int out_size, void* d_ws, size_t ws_size,
                              hipStream_t stream) {
  const float* y0   = (const float*)d_in[0];
  const float* Win  = (const float*)d_in[1];
  const float* bin  = (const float*)d_in[2];
  const float* Whid = (const float*)d_in[3];
  const float* bhid = (const float*)d_in[4];
  const float* Wout = (const float*)d_in[5];
  const float* bout = (const float*)d_in[6];
  const float* eps  = (const float*)d_in[7];
  float* out = (float*)d_out;
  (void)in_sizes; (void)n_in; (void)out_size; (void)d_ws; (void)ws_size;

  reset_kernel<<<dim3(1), dim3(BLK), 0, stream>>>();
  ode_kernel<<<dim3(NBLK), dim3(BLK), 0, stream>>>(y0, Win, bin, Whid, bhid, Wout, bout, eps, out);
}

// Round 3
// 19452.486 us; speedup vs baseline: 1.6853x; 1.1965x over previous
//
#include <hip/hip_runtime.h>
#include <math.h>

#define NBLK 192
#define BLK  256
#define NSTATE 3072
#define HID  768

__device__ const float d_AT[7][6] = {
  {0.f,0.f,0.f,0.f,0.f,0.f},
  {0.161f,0.f,0.f,0.f,0.f,0.f},
  {-0.008480655492356989f,0.335480655492357f,0.f,0.f,0.f,0.f},
  {2.8971530571054935f,-6.359448489975075f,4.3622954328695815f,0.f,0.f,0.f},
  {5.325864828439257f,-11.748883564062828f,7.4955393428898365f,-0.09249506636175525f,0.f,0.f},
  {5.86145544294642f,-12.92096931784711f,8.159367898576159f,-0.071584973281401f,-0.028269050394068383f,0.f},
  {0.09646076681806523f,0.01f,0.4798896504144996f,1.379008574103742f,-3.290069515436081f,2.324710524099774f},
};
__device__ const float d_EC[7] = {
  -0.001780011052226f,-0.000816434459657f,0.007880878010262f,-0.144711007173263f,
   0.582357165452555f,-0.458082105929187f,0.015151515151515152f };

struct alignas(128) ASlot { unsigned v; unsigned pad[31]; };
__device__ ASlot g_arr[NBLK];
__device__ __align__(16) float g_y[2][NSTATE];
__device__ __align__(16) float g_k[7][NSTATE];
__device__ __align__(16) float g_z[NSTATE];
__device__ __align__(16) float g_h[2][HID];
__device__ float g_part[NBLK];

__global__ void reset_kernel(){
  if (threadIdx.x < NBLK)
    __hip_atomic_store(&g_arr[threadIdx.x].v, 0u, __ATOMIC_RELAXED, __HIP_MEMORY_SCOPE_AGENT);
}

// ---- relaxed agent-scope (LLC-coherent, L2-bypassing) data movers ----
__device__ __forceinline__ float2 ldv2(const float* p){
  unsigned long long u = __hip_atomic_load(reinterpret_cast<const unsigned long long*>(p),
                                           __ATOMIC_RELAXED, __HIP_MEMORY_SCOPE_AGENT);
  float2 r; __builtin_memcpy(&r, &u, 8); return r;
}
__device__ __forceinline__ void stv2(float* p, float2 v){
  unsigned long long u; __builtin_memcpy(&u, &v, 8);
  __hip_atomic_store(reinterpret_cast<unsigned long long*>(p), u,
                     __ATOMIC_RELAXED, __HIP_MEMORY_SCOPE_AGENT);
}
__device__ __forceinline__ float ldv1(const float* p){
  unsigned u = __hip_atomic_load(reinterpret_cast<const unsigned*>(p),
                                 __ATOMIC_RELAXED, __HIP_MEMORY_SCOPE_AGENT);
  float r; __builtin_memcpy(&r, &u, 4); return r;
}
__device__ __forceinline__ void stv1(float* p, float v){
  unsigned u; __builtin_memcpy(&u, &v, 4);
  __hip_atomic_store(reinterpret_cast<unsigned*>(p), u,
                     __ATOMIC_RELAXED, __HIP_MEMORY_SCOPE_AGENT);
}

__device__ __forceinline__ float softplus_f(float x){
  return fmaxf(x, 0.0f) + log1pf(expf(-fabsf(x)));
}

// Barrier with NO cache maintenance: all threads drain their own stores (vmcnt),
// block sync, thread0 release-stores its slot, threads 0..NBLK-1 poll relaxed.
// No acquire anywhere -> per-XCD L2 (weights) never invalidated.
__device__ __forceinline__ void gsync(unsigned& epoch){
  const unsigned e = epoch + 1u;
  asm volatile("s_waitcnt vmcnt(0)" ::: "memory");
  __syncthreads();
  if (threadIdx.x == 0)
    __hip_atomic_store(&g_arr[blockIdx.x].v, e, __ATOMIC_RELEASE, __HIP_MEMORY_SCOPE_AGENT);
  if (threadIdx.x < NBLK){
    unsigned guard = 0;
    while (__hip_atomic_load(&g_arr[threadIdx.x].v, __ATOMIC_RELAXED, __HIP_MEMORY_SCOPE_AGENT) < e){
      __builtin_amdgcn_s_sleep(2);
      if (++guard > (1u<<18)) break;   // fail visibly, don't hang
    }
  }
  __syncthreads();
  epoch = e;
}

__global__ __launch_bounds__(BLK)
void ode_kernel(const float* __restrict__ y0p,
                const float* __restrict__ Win,  const float* __restrict__ bin,
                const float* __restrict__ Whid, const float* __restrict__ bhid,
                const float* __restrict__ Wout, const float* __restrict__ bout,
                const float* __restrict__ eps,  float* __restrict__ out)
{
  __shared__ float zs[NSTATE];
  __shared__ float hst[HID];
  __shared__ float kc[7][16];      // this block's k-row slice, all 7 stages
  __shared__ float ysl_s[16], y1sl_s[16];
  __shared__ float red[4];

  const int tid  = threadIdx.x, blk = blockIdx.x;
  const int wave = tid >> 6, lane = tid & 63;
  const int l16  = lane & 15, rq = lane >> 4;
  const int row1 = blk*4 + wave;                 // l1 / hidden row (1 wave per row)
  const int rowo = blk*16 + wave*4 + rq;         // out row (16 lanes per row)
  unsigned epoch = 0;

  // weight bases (rows fixed per thread; stays cached in this XCD's L2 forever)
  const float4* w1  = reinterpret_cast<const float4*>(Win  + (size_t)row1*NSTATE) + lane;
  const float4* wh0 = reinterpret_cast<const float4*>(Whid + ((size_t)0*HID + row1)*HID) + lane;
  const float4* wh1 = reinterpret_cast<const float4*>(Whid + ((size_t)1*HID + row1)*HID) + lane;
  const float4* wh2 = reinterpret_cast<const float4*>(Whid + ((size_t)2*HID + row1)*HID) + lane;
  const float4* wo  = reinterpret_cast<const float4*>(Wout + (size_t)rowo*HID) + l16;
  const float b1 = bin[row1];
  const float bh0v = bhid[row1], bh1v = bhid[HID+row1], bh2v = bhid[2*HID+row1];
  const float bo = bout[rowo];

  int cur = 0, kpar = 0;
  auto kslot = [&](int j){ return (j==1) ? (kpar?6:0) : (j==7) ? (kpar?0:6) : (j-1); };

  // ---- init: y slice to regs/LDS + g_y[0]; output row 0 ----
  if (tid < 16){
    const int e = blk*16 + tid;
    float v = y0p[e];
    ysl_s[tid] = v;
    stv1(&g_y[0][e], v);
  }
  if (tid < 4){
    const int e = blk*4 + tid;
    out[e] = y0p[e] + eps[e]*y0p[HID+e];
  }
  gsync(epoch);

  auto feval = [&](int st, float dte){
    // ======== phase A: stage z -> LDS; layer1; write h1 -> g_h[0] ========
    float2* zs2 = reinterpret_cast<float2*>(zs);
    if (st == 0){
      const float4* y04 = reinterpret_cast<const float4*>(y0p);
      float4* zs4 = reinterpret_cast<float4*>(zs);
      #pragma unroll
      for (int r = 0; r < 3; ++r){ const int i = tid + BLK*r; zs4[i] = y04[i]; }
    } else if (st == 1){
      const float* yc = g_y[cur];
      const float* k1 = g_k[kslot(1)];
      const float c = dte * d_AT[1][0];
      #pragma unroll
      for (int r = 0; r < 6; ++r){
        const int i = tid + BLK*r;
        float2 yv = ldv2(yc + 2*i);
        float2 kv = ldv2(k1 + 2*i);
        float2 zv; zv.x = yv.x + c*kv.x; zv.y = yv.y + c*kv.y;
        zs2[i] = zv;
      }
    } else {
      #pragma unroll
      for (int r = 0; r < 6; ++r){
        const int i = tid + BLK*r;
        zs2[i] = ldv2(g_z + 2*i);
      }
    }
    __syncthreads();
    {
      const float4* zl = reinterpret_cast<const float4*>(zs) + lane;
      float acc = 0.f;
      #pragma unroll
      for (int i2 = 0; i2 < 12; ++i2){
        float4 w = w1[64*i2]; float4 x = zl[64*i2];
        acc = fmaf(w.x,x.x, fmaf(w.y,x.y, fmaf(w.z,x.z, fmaf(w.w,x.w, acc))));
      }
      acc += __shfl_xor(acc,32); acc += __shfl_xor(acc,16); acc += __shfl_xor(acc,8);
      acc += __shfl_xor(acc,4);  acc += __shfl_xor(acc,2);  acc += __shfl_xor(acc,1);
      if (lane == 0) stv1(&g_h[0][row1], softplus_f(acc + b1));
    }
    gsync(epoch);

    // ======== hidden layers ========
    float2* hst2 = reinterpret_cast<float2*>(hst);
    #pragma unroll
    for (int l = 0; l < 3; ++l){
      const int src = (l == 1) ? 1 : 0;       // 0,1,0
      const int dst = src ^ 1;                // 1,0,1
      #pragma unroll
      for (int r = 0; r < 2; ++r){
        const int i = tid + BLK*r;
        if (i < HID/2) hst2[i] = ldv2(g_h[src] + 2*i);
      }
      __syncthreads();
      const float4* wh = (l==0) ? wh0 : (l==1) ? wh1 : wh2;
      const float bh = (l==0) ? bh0v : (l==1) ? bh1v : bh2v;
      const float4* hx = reinterpret_cast<const float4*>(hst) + lane;
      float acc = 0.f;
      #pragma unroll
      for (int i2 = 0; i2 < 3; ++i2){
        float4 w = wh[64*i2]; float4 x = hx[64*i2];
        acc = fmaf(w.x,x.x, fmaf(w.y,x.y, fmaf(w.z,x.z, fmaf(w.w,x.w, acc))));
      }
      acc += __shfl_xor(acc,32); acc += __shfl_xor(acc,16); acc += __shfl_xor(acc,8);
      acc += __shfl_xor(acc,4);  acc += __shfl_xor(acc,2);  acc += __shfl_xor(acc,1);
      if (lane == 0) stv1(&g_h[dst][row1], softplus_f(acc + bh));
      gsync(epoch);
    }

    // ======== phase E: out layer; local z-slice / y1 / err folding ========
    #pragma unroll
    for (int r = 0; r < 2; ++r){
      const int i = tid + BLK*r;
      if (i < HID/2) hst2[i] = ldv2(g_h[1] + 2*i);
    }
    __syncthreads();
    const int ds = kslot(st + 1);   // logical k_{st+1}
    {
      const float4* hx = reinterpret_cast<const float4*>(hst) + l16;
      float acc = 0.f;
      #pragma unroll
      for (int i2 = 0; i2 < 12; ++i2){
        float4 w = wo[16*i2]; float4 x = hx[16*i2];
        acc = fmaf(w.x,x.x, fmaf(w.y,x.y, fmaf(w.z,x.z, fmaf(w.w,x.w, acc))));
      }
      acc += __shfl_xor(acc,8); acc += __shfl_xor(acc,4);
      acc += __shfl_xor(acc,2); acc += __shfl_xor(acc,1);
      if (l16 == 0){
        const float kv = acc + bo;
        kc[ds][wave*4 + rq] = kv;
        if (st == 0 || st == 6) stv1(&g_k[ds][rowo], kv);   // only k1/k7 needed globally
      }
    }
    __syncthreads();
    if (st >= 1 && st <= 5 && tid < 16){
      const int ns = st + 1;
      float s = 0.f;
      for (int j = 1; j <= ns; ++j) s += d_AT[ns][j-1] * kc[kslot(j)][tid];
      const float zv = ysl_s[tid] + dte * s;
      stv1(&g_z[blk*16 + tid], zv);
      if (st == 5){ y1sl_s[tid] = zv; stv1(&g_y[cur^1][blk*16 + tid], zv); }
    }
    if (st == 6 && tid < 16){
      float ev = 0.f;
      for (int j = 1; j <= 7; ++j) ev += d_EC[j-1] * kc[kslot(j)][tid];
      ev *= dte;
      const float sc = 1e-6f + 1e-3f * fmaxf(fabsf(ysl_s[tid]), fabsf(y1sl_s[tid]));
      const float q = ev / sc;
      float v = q*q;
      v += __shfl_xor(v,8); v += __shfl_xor(v,4); v += __shfl_xor(v,2); v += __shfl_xor(v,1);
      if (tid == 0) stv1(&g_part[blk], v);
    }
    gsync(epoch);
  };

  // k1 = f(y0) once; FSAL-carried thereafter
  feval(0, 0.f);

  float t = 0.f, dtv = 0.1f;
  for (int iv = 1; iv < 100; ++iv){
    const float t1 = (float)iv / 99.0f;
    for (int a = 0; a < 6; ++a){
      if (t >= t1 - 1e-10f) break;
      const float dte = fminf(dtv, t1 - t);

      feval(1, dte); feval(2, dte); feval(3, dte);
      feval(4, dte); feval(5, dte); feval(6, dte);

      // deterministic err: every block sums 192 partials in fixed order
      float v = 0.f;
      if (tid < NBLK) v = ldv1(&g_part[tid]);
      v += __shfl_xor(v,32); v += __shfl_xor(v,16); v += __shfl_xor(v,8);
      v += __shfl_xor(v,4);  v += __shfl_xor(v,2);  v += __shfl_xor(v,1);
      if (lane == 0) red[wave] = v;
      __syncthreads();
      const float err = sqrtf((red[0]+red[1]+red[2]) * (1.0f/3072.0f));
      __syncthreads();

      const bool accept = (err <= 1.0f);
      const float factor = fminf(fmaxf(0.9f * powf(fmaxf(err, 1e-10f), -0.2f), 0.2f), 10.0f);
      if (accept){
        t += dte;
        if (tid < 16) ysl_s[tid] = y1sl_s[tid];
        cur ^= 1; kpar ^= 1;
      }
      dtv = dte * factor;
      __syncthreads();
    }
    t = t1;
    if (tid < 4){
      const int e = blk*4 + tid;
      const float m = ldv1(&g_y[cur][e]);
      const float s = ldv1(&g_y[cur][HID + e]);
      out[(size_t)iv*HID + e] = m + eps[(size_t)iv*HID + e]*s;
    }
  }
}

extern "C" void kernel_launch(void* const* d_in, const int* in_sizes, int n_in,
                              void* d_out, int out_size, void* d_ws, size_t ws_size,
                              hipStream_t stream) {
  const float* y0   = (const float*)d_in[0];
  const float* Win  = (const float*)d_in[1];
  const float* bin  = (const float*)d_in[2];
  const float* Whid = (const float*)d_in[3];
  const float* bhid = (const float*)d_in[4];
  const float* Wout = (const float*)d_in[5];
  const float* bout = (const float*)d_in[6];
  const float* eps  = (const float*)d_in[7];
  float* out = (float*)d_out;
  (void)in_sizes; (void)n_in; (void)out_size; (void)d_ws; (void)ws_size;

  reset_kernel<<<dim3(1), dim3(BLK), 0, stream>>>();
  ode_kernel<<<dim3(NBLK), dim3(BLK), 0, stream>>>(y0, Win, bin, Whid, bhid, Wout, bout, eps, out);
}

// Round 5
// 14333.014 us; speedup vs baseline: 2.2873x; 1.3572x over previous
//
#include <hip/hip_runtime.h>
#include <math.h>

#define NBLK 192
#define BLK  256
#define NSTATE 3072
#define HID  768
typedef unsigned long long u64;
typedef unsigned int u32;

__device__ const float d_AT[7][6] = {
  {0.f,0.f,0.f,0.f,0.f,0.f},
  {0.161f,0.f,0.f,0.f,0.f,0.f},
  {-0.008480655492356989f,0.335480655492357f,0.f,0.f,0.f,0.f},
  {2.8971530571054935f,-6.359448489975075f,4.3622954328695815f,0.f,0.f,0.f},
  {5.325864828439257f,-11.748883564062828f,7.4955393428898365f,-0.09249506636175525f,0.f,0.f},
  {5.86145544294642f,-12.92096931784711f,8.159367898576159f,-0.071584973281401f,-0.028269050394068383f,0.f},
  {0.09646076681806523f,0.01f,0.4798896504144996f,1.379008574103742f,-3.290069515436081f,2.324710524099774f},
};
__device__ const float d_EC[7] = {
  -0.001780011052226f,-0.000816434459657f,0.007880878010262f,-0.144711007173263f,
   0.582357165452555f,-0.458082105929187f,0.015151515151515152f };

// Cross-block state: {tag:hi32, value:lo32} words, ping-pong buffered per sequence.
struct GT { u64 h[2][HID]; u64 z[2][NSTATE]; u64 y[2][NSTATE]; u64 p[2][NBLK]; };
__device__ GT gt;
__device__ int g_abort;

__global__ void reset_kernel(){
  u64* w = reinterpret_cast<u64*>(&gt);
  const int n = (int)(sizeof(GT)/8);
  for (int i = blockIdx.x*blockDim.x + threadIdx.x; i < n; i += gridDim.x*blockDim.x)
    __hip_atomic_store(w + i, 0ull, __ATOMIC_RELAXED, __HIP_MEMORY_SCOPE_AGENT);
  if (blockIdx.x == 0 && threadIdx.x == 0)
    __hip_atomic_store(&g_abort, 0, __ATOMIC_RELAXED, __HIP_MEMORY_SCOPE_AGENT);
}

__device__ __forceinline__ int abort_now(){
  return __hip_atomic_load(&g_abort, __ATOMIC_RELAXED, __HIP_MEMORY_SCOPE_AGENT);
}
__device__ __forceinline__ void raise_abort(){
  __hip_atomic_store(&g_abort, 1, __ATOMIC_RELAXED, __HIP_MEMORY_SCOPE_AGENT);
}
__device__ __forceinline__ void stT(u64* p, u32 tag, float v){
  u32 b; __builtin_memcpy(&b, &v, 4);
  __hip_atomic_store(p, ((u64)tag << 32) | (u64)b, __ATOMIC_RELAXED, __HIP_MEMORY_SCOPE_AGENT);
}
// Single tagged-word poll. Always terminates: guard bail raises g_abort; abort short-circuits.
__device__ __forceinline__ float pollT1(const u64* p, u32 tag){
  u64* q = const_cast<u64*>(p);
  u64 w = __hip_atomic_load(q, __ATOMIC_RELAXED, __HIP_MEMORY_SCOPE_AGENT);
  u32 guard = 0;
  while ((u32)(w >> 32) != tag){
    if ((guard & 255u) == 255u && abort_now()) break;
    if (++guard > (1u<<19)){ raise_abort(); break; }
    __builtin_amdgcn_s_sleep(1);
    w = __hip_atomic_load(q, __ATOMIC_RELAXED, __HIP_MEMORY_SCOPE_AGENT);
  }
  u32 b = (u32)w; float v; __builtin_memcpy(&v, &b, 4); return v;
}
// Batched poll: N words/thread (stride BLK); first loads pipelined; re-poll stale only.
template<int N>
__device__ __forceinline__ void pollN(const u64* src, u32 tag, float* dst){
  const int tid = threadIdx.x;
  u64* s = const_cast<u64*>(src);
  u64 w[N];
  #pragma unroll
  for (int r = 0; r < N; ++r)
    w[r] = __hip_atomic_load(s + tid + BLK*r, __ATOMIC_RELAXED, __HIP_MEMORY_SCOPE_AGENT);
  u32 guard = 0;
  for (;;){
    bool all = true;
    #pragma unroll
    for (int r = 0; r < N; ++r) if ((u32)(w[r] >> 32) != tag) all = false;
    if (all) break;
    if ((guard & 255u) == 255u && abort_now()) break;
    if (++guard > (1u<<19)){ raise_abort(); break; }
    __builtin_amdgcn_s_sleep(1);
    #pragma unroll
    for (int r = 0; r < N; ++r)
      if ((u32)(w[r] >> 32) != tag)
        w[r] = __hip_atomic_load(s + tid + BLK*r, __ATOMIC_RELAXED, __HIP_MEMORY_SCOPE_AGENT);
  }
  #pragma unroll
  for (int r = 0; r < N; ++r){
    u32 b = (u32)w[r]; float v; __builtin_memcpy(&v, &b, 4);
    dst[tid + BLK*r] = v;
  }
}

__device__ __forceinline__ float softplus_f(float x){
  return fmaxf(x, 0.0f) + log1pf(expf(-fabsf(x)));
}

__global__ __launch_bounds__(BLK)
void ode_kernel(const float* __restrict__ y0p,
                const float* __restrict__ Win,  const float* __restrict__ bin,
                const float* __restrict__ Whid, const float* __restrict__ bhid,
                const float* __restrict__ Wout, const float* __restrict__ bout,
                const float* __restrict__ eps,  float* __restrict__ out)
{
  __shared__ float zsh[NSTATE];
  __shared__ float hsh[HID];
  __shared__ float kc[7][16];
  __shared__ float ysl[16], y1sl[16];
  __shared__ float red[4];
  __shared__ int s_ab;

  const int tid  = threadIdx.x, blk = blockIdx.x;
  const int wave = tid >> 6, lane = tid & 63;
  const int l16  = lane & 15;
  const int ro   = tid >> 4;                 // local out-row 0..15
  const int row1 = blk*4 + wave;             // layer1/hidden row (1 wave per row)
  const int rowo = blk*16 + ro;              // out row (16 lanes per row)

  // per-thread weight bases (L2-resident; proven pattern from round 3)
  const float4* w1  = reinterpret_cast<const float4*>(Win  + (size_t)row1*NSTATE) + lane;
  const float4* wh0 = reinterpret_cast<const float4*>(Whid + ((size_t)0*HID + row1)*HID) + lane;
  const float4* wh1 = reinterpret_cast<const float4*>(Whid + ((size_t)1*HID + row1)*HID) + lane;
  const float4* wh2 = reinterpret_cast<const float4*>(Whid + ((size_t)2*HID + row1)*HID) + lane;
  const float4* wo  = reinterpret_cast<const float4*>(Wout + (size_t)rowo*HID) + l16;
  const float b1 = bin[row1];
  const float bh0 = bhid[row1], bh1 = bhid[HID+row1], bh2 = bhid[2*HID+row1];
  const float bo = bout[rowo];

  if (tid < 16) ysl[tid] = y0p[blk*16 + tid];
  if (tid < 4){ const int e = blk*4 + tid; out[e] = y0p[e] + eps[e]*y0p[HID+e]; }
  __syncthreads();

  u32 hseq = 0, zseq = 0, yseq = 0, pseq = 0;
  u32 y_tag = 0; int y_buf = 0;
  int kpar = 0;
  auto kslot = [&](int j){ return (j==1) ? (kpar?6:0) : (j==7) ? (kpar?0:6) : (j-1); };

  auto feval = [&](int st, float dte){
    // ---- acquire z ----
    if (st == 0){
      const float4* s4 = reinterpret_cast<const float4*>(y0p);
      float4* d4 = reinterpret_cast<float4*>(zsh);
      #pragma unroll
      for (int r = 0; r < 3; ++r) d4[tid + BLK*r] = s4[tid + BLK*r];
    } else {
      pollN<12>(gt.z[zseq&1], zseq, zsh);
    }
    __syncthreads();
    // ---- layer 1: 768x3072, 1 wave/row ----
    {
      const float4* zl = reinterpret_cast<const float4*>(zsh) + lane;
      float acc = 0.f;
      #pragma unroll
      for (int i = 0; i < 12; ++i){
        float4 w = w1[64*i], x = zl[64*i];
        acc = fmaf(w.x,x.x, fmaf(w.y,x.y, fmaf(w.z,x.z, fmaf(w.w,x.w, acc))));
      }
      acc += __shfl_xor(acc,32); acc += __shfl_xor(acc,16); acc += __shfl_xor(acc,8);
      acc += __shfl_xor(acc,4);  acc += __shfl_xor(acc,2);  acc += __shfl_xor(acc,1);
      ++hseq;
      if (lane == 0) stT(&gt.h[hseq&1][row1], hseq, softplus_f(acc + b1));
    }
    // ---- 3 hidden layers: 768x768 ----
    #pragma unroll
    for (int l = 0; l < 3; ++l){
      pollN<3>(gt.h[hseq&1], hseq, hsh);
      __syncthreads();
      const float4* wr = (l==0) ? wh0 : (l==1) ? wh1 : wh2;
      const float bh  = (l==0) ? bh0 : (l==1) ? bh1 : bh2;
      const float4* hx = reinterpret_cast<const float4*>(hsh) + lane;
      float acc = 0.f;
      #pragma unroll
      for (int i = 0; i < 3; ++i){
        float4 w = wr[64*i], x = hx[64*i];
        acc = fmaf(w.x,x.x, fmaf(w.y,x.y, fmaf(w.z,x.z, fmaf(w.w,x.w, acc))));
      }
      acc += __shfl_xor(acc,32); acc += __shfl_xor(acc,16); acc += __shfl_xor(acc,8);
      acc += __shfl_xor(acc,4);  acc += __shfl_xor(acc,2);  acc += __shfl_xor(acc,1);
      ++hseq;
      if (lane == 0) stT(&gt.h[hseq&1][row1], hseq, softplus_f(acc + bh));
      __syncthreads();            // hsh stable until every lane finished reading
    }
    // ---- out layer: 3072x768, 16 lanes/row; k-slice stays block-local ----
    pollN<3>(gt.h[hseq&1], hseq, hsh);
    __syncthreads();
    {
      const float4* hx = reinterpret_cast<const float4*>(hsh) + l16;
      float acc = 0.f;
      #pragma unroll
      for (int i = 0; i < 12; ++i){
        float4 w = wo[16*i], x = hx[16*i];
        acc = fmaf(w.x,x.x, fmaf(w.y,x.y, fmaf(w.z,x.z, fmaf(w.w,x.w, acc))));
      }
      acc += __shfl_xor(acc,8); acc += __shfl_xor(acc,4);
      acc += __shfl_xor(acc,2); acc += __shfl_xor(acc,1);
      if (l16 == 0) kc[kslot(st+1)][ro] = acc + bo;
    }
    __syncthreads();
    // ---- local folding: next-stage z / y1 / err partial ----
    if (st >= 1 && st <= 5){
      ++zseq;
      if (st == 5) ++yseq;
      if (tid < 16){
        float s = 0.f;
        for (int j = 1; j <= st+1; ++j) s += d_AT[st+1][j-1] * kc[kslot(j)][tid];
        const float zv = ysl[tid] + dte * s;
        stT(&gt.z[zseq&1][blk*16 + tid], zseq, zv);
        if (st == 5){ y1sl[tid] = zv; stT(&gt.y[yseq&1][blk*16 + tid], yseq, zv); }
      }
    }
    if (st == 6){
      ++pseq;
      if (tid < 16){
        float ev = 0.f;
        for (int j = 1; j <= 7; ++j) ev += d_EC[j-1] * kc[kslot(j)][tid];
        ev *= dte;
        const float sc = 1e-6f + 1e-3f * fmaxf(fabsf(ysl[tid]), fabsf(y1sl[tid]));
        const float q = ev / sc;
        float v = q*q;
        v += __shfl_xor(v,8); v += __shfl_xor(v,4); v += __shfl_xor(v,2); v += __shfl_xor(v,1);
        if (tid == 0) stT(&gt.p[pseq&1][blk], pseq, v);
      }
    }
  };

  // k1 = f(y0) once; FSAL-carried afterwards
  feval(0, 0.f);

  float t = 0.f, dtv = 0.1f;
  for (int iv = 1; iv < 100; ++iv){
    const float t1 = (float)iv / 99.0f;
    for (int a = 0; a < 6; ++a){
      if (t >= t1 - 1e-10f) break;
      // uniform abort checkpoint (fail fast, never wedge)
      if (tid == 0) s_ab = abort_now();
      __syncthreads();
      if (s_ab) return;
      const float dte = fminf(dtv, t1 - t);

      // z for stage 2 (block-local k1 slice)
      ++zseq;
      if (tid < 16)
        stT(&gt.z[zseq&1][blk*16 + tid], zseq, ysl[tid] + dte * 0.161f * kc[kslot(1)][tid]);

      feval(1,dte); feval(2,dte); feval(3,dte);
      feval(4,dte); feval(5,dte); feval(6,dte);

      // err: poll 192 tagged partials, deterministic fixed-order reduce
      float v = 0.f;
      if (tid < NBLK) v = pollT1(&gt.p[pseq&1][tid], pseq);
      v += __shfl_xor(v,32); v += __shfl_xor(v,16); v += __shfl_xor(v,8);
      v += __shfl_xor(v,4);  v += __shfl_xor(v,2);  v += __shfl_xor(v,1);
      if (lane == 0) red[wave] = v;
      __syncthreads();
      const float err = sqrtf((red[0]+red[1]+red[2]+red[3]) * (1.0f/3072.0f));
      __syncthreads();

      const bool accept = (err <= 1.0f);
      const float factor = fminf(fmaxf(0.9f * powf(fmaxf(err, 1e-10f), -0.2f), 0.2f), 10.0f);
      if (accept){
        t += dte;
        if (tid < 16) ysl[tid] = y1sl[tid];
        kpar ^= 1;
        y_tag = yseq; y_buf = (int)(yseq & 1);
      }
      dtv = dte * factor;
      __syncthreads();
    }
    t = t1;
    // emit output row iv (cross-block y slices, tagged)
    if (tid < 4){
      const int e = blk*4 + tid;
      float m, s;
      if (y_tag == 0u){ m = y0p[e]; s = y0p[HID + e]; }
      else {
        m = pollT1(&gt.y[y_buf][e],       y_tag);
        s = pollT1(&gt.y[y_buf][HID + e], y_tag);
      }
      out[(size_t)iv*HID + e] = m + eps[(size_t)iv*HID + e]*s;
    }
  }
}

extern "C" void kernel_launch(void* const* d_in, const int* in_sizes, int n_in,
                              void* d_out, int out_size, void* d_ws, size_t ws_size,
                              hipStream_t stream) {
  const float* y0   = (const float*)d_in[0];
  const float* Win  = (const float*)d_in[1];
  const float* bin  = (const float*)d_in[2];
  const float* Whid = (const float*)d_in[3];
  const float* bhid = (const float*)d_in[4];
  const float* Wout = (const float*)d_in[5];
  const float* bout = (const float*)d_in[6];
  const float* eps  = (const float*)d_in[7];
  float* out = (float*)d_out;
  (void)in_sizes; (void)n_in; (void)out_size; (void)d_ws; (void)ws_size;

  reset_kernel<<<dim3(56), dim3(BLK), 0, stream>>>();
  ode_kernel<<<dim3(NBLK), dim3(BLK), 0, stream>>>(y0, Win, bin, Whid, bhid, Wout, bout, eps, out);
}

// Round 6
// 13890.877 us; speedup vs baseline: 2.3601x; 1.0318x over previous
//
#include <hip/hip_runtime.h>
#include <math.h>

#define NBLK 192
#define BLK  256
#define NSTATE 3072
#define HID  768
typedef unsigned long long u64;
typedef unsigned int u32;

__device__ const float d_AT[7][6] = {
  {0.f,0.f,0.f,0.f,0.f,0.f},
  {0.161f,0.f,0.f,0.f,0.f,0.f},
  {-0.008480655492356989f,0.335480655492357f,0.f,0.f,0.f,0.f},
  {2.8971530571054935f,-6.359448489975075f,4.3622954328695815f,0.f,0.f,0.f},
  {5.325864828439257f,-11.748883564062828f,7.4955393428898365f,-0.09249506636175525f,0.f,0.f},
  {5.86145544294642f,-12.92096931784711f,8.159367898576159f,-0.071584973281401f,-0.028269050394068383f,0.f},
  {0.09646076681806523f,0.01f,0.4798896504144996f,1.379008574103742f,-3.290069515436081f,2.324710524099774f},
};
__device__ const float d_EC[7] = {
  -0.001780011052226f,-0.000816434459657f,0.007880878010262f,-0.144711007173263f,
   0.582357165452555f,-0.458082105929187f,0.015151515151515152f };

// per-block monotone phase counter, one cacheline each
struct alignas(128) PC { u32 v; u32 pad[31]; };
__device__ PC g_pc[NBLK];
__device__ int g_abort;
// raw (untagged) exchange buffers; visibility gated by counters
__device__ __align__(16) float g_z[NSTATE];
__device__ __align__(16) float g_h[2][HID];
__device__ float g_p[NBLK];
__device__ __align__(16) float g_ypub[NSTATE];

__global__ void reset_kernel(){
  const int i = blockIdx.x*blockDim.x + threadIdx.x;
  if (i < NBLK) __hip_atomic_store(&g_pc[i].v, 0u, __ATOMIC_RELAXED, __HIP_MEMORY_SCOPE_AGENT);
  if (i == 0)   __hip_atomic_store(&g_abort, 0, __ATOMIC_RELAXED, __HIP_MEMORY_SCOPE_AGENT);
}

__device__ __forceinline__ int abort_now(){
  return __hip_atomic_load(&g_abort, __ATOMIC_RELAXED, __HIP_MEMORY_SCOPE_AGENT);
}
__device__ __forceinline__ void raise_abort(){
  __hip_atomic_store(&g_abort, 1, __ATOMIC_RELAXED, __HIP_MEMORY_SCOPE_AGENT);
}
// relaxed agent-scope (LLC-coherent, L2-bypassing) movers
__device__ __forceinline__ void st1(float* p, float v){
  u32 b; __builtin_memcpy(&b,&v,4);
  __hip_atomic_store(reinterpret_cast<u32*>(p), b, __ATOMIC_RELAXED, __HIP_MEMORY_SCOPE_AGENT);
}
__device__ __forceinline__ float ld1(const float* p){
  u32 b = __hip_atomic_load(reinterpret_cast<u32*>(const_cast<float*>(p)),
                            __ATOMIC_RELAXED, __HIP_MEMORY_SCOPE_AGENT);
  float v; __builtin_memcpy(&v,&b,4); return v;
}
__device__ __forceinline__ float2 ld2(const float* p){
  u64 b = __hip_atomic_load(reinterpret_cast<u64*>(const_cast<float*>(p)),
                            __ATOMIC_RELAXED, __HIP_MEMORY_SCOPE_AGENT);
  float2 v; __builtin_memcpy(&v,&b,8); return v;
}

__device__ __forceinline__ float softplus_f(float x){
  return fmaxf(x, 0.0f) + log1pf(expf(-fabsf(x)));
}

__global__ __launch_bounds__(BLK)
void ode_kernel(const float* __restrict__ y0p,
                const float* __restrict__ Win,  const float* __restrict__ bin,
                const float* __restrict__ Whid, const float* __restrict__ bhid,
                const float* __restrict__ Wout, const float* __restrict__ bout,
                const float* __restrict__ eps,  float* __restrict__ out)
{
  __shared__ float zsh[NSTATE];
  __shared__ float hsh[HID];
  __shared__ float kc[7][16];
  __shared__ float ysl[16], y1sl[16];
  __shared__ float red[4];
  __shared__ int s_ab;

  const int tid  = threadIdx.x, blk = blockIdx.x;
  const int wave = tid >> 6, lane = tid & 63;
  const int l16  = lane & 15;
  const int ro   = tid >> 4;
  const int row1 = blk*4 + wave;
  const int rowo = blk*16 + ro;

  const float4* w1  = reinterpret_cast<const float4*>(Win  + (size_t)row1*NSTATE) + lane;
  const float4* wh0 = reinterpret_cast<const float4*>(Whid + ((size_t)0*HID + row1)*HID) + lane;
  const float4* wh1 = reinterpret_cast<const float4*>(Whid + ((size_t)1*HID + row1)*HID) + lane;
  const float4* wh2 = reinterpret_cast<const float4*>(Whid + ((size_t)2*HID + row1)*HID) + lane;
  const float4* wo  = reinterpret_cast<const float4*>(Wout + (size_t)rowo*HID) + l16;
  const float b1 = bin[row1];
  const float bh0 = bhid[row1], bh1 = bhid[HID+row1], bh2 = bhid[2*HID+row1];
  const float bo = bout[rowo];

  u32 ph = 0;        // global publish count (lockstep-identical on all blocks)
  int hb = 0;        // h ping-pong index (toggled before each h publish)
  int kpar = 0;
  auto kslot = [&](int j){ return (j==1) ? (kpar?6:0) : (j==7) ? (kpar?0:6) : (j-1); };

  // publish: drain own stores to LLC, then bump my counter
  auto publish = [&](){
    ++ph;
    asm volatile("s_waitcnt vmcnt(0)" ::: "memory");
    __syncthreads();
    if (tid == 0)
      __hip_atomic_store(&g_pc[blk].v, ph, __ATOMIC_RELAXED, __HIP_MEMORY_SCOPE_AGENT);
  };
  // wait until every block has published phase >= ph
  auto poll_all = [&](){
    if (tid < NBLK){
      u32 guard = 0;
      while (__hip_atomic_load(&g_pc[tid].v, __ATOMIC_RELAXED, __HIP_MEMORY_SCOPE_AGENT) < ph){
        if ((++guard & 1023u) == 0u && abort_now()) break;
        if (guard > (1u<<18)){ raise_abort(); break; }
        __builtin_amdgcn_s_sleep(1);
      }
    }
    __syncthreads();
  };

  if (tid < 16) ysl[tid] = y0p[blk*16 + tid];
  if (tid < 4){ const int e = blk*4 + tid; out[e] = y0p[e] + eps[e]*y0p[HID+e]; }
  __syncthreads();

  auto load_h = [&](){
    { float2 v = ld2(g_h[hb] + 2*tid); reinterpret_cast<float2*>(hsh)[tid] = v; }
    if (tid < 128){ const int i = tid + 256; float2 v = ld2(g_h[hb] + 2*i);
                    reinterpret_cast<float2*>(hsh)[i] = v; }
    __syncthreads();
  };

  auto feval = [&](int st, float dte){
    // ---- acquire z ----
    if (st == 0){
      const float4* s4 = reinterpret_cast<const float4*>(y0p);
      float4* d4 = reinterpret_cast<float4*>(zsh);
      #pragma unroll
      for (int r = 0; r < 3; ++r) d4[tid + BLK*r] = s4[tid + BLK*r];
    } else {
      poll_all();                     // z' published as current ph
      #pragma unroll
      for (int r = 0; r < 6; ++r){
        const int i = tid + BLK*r;    // u64 index < 1536
        float2 v = ld2(g_z + 2*i);
        reinterpret_cast<float2*>(zsh)[i] = v;
      }
    }
    __syncthreads();
    // ---- layer 1: 768x3072, 1 wave/row ----
    {
      const float4* zl = reinterpret_cast<const float4*>(zsh) + lane;
      float acc = 0.f;
      #pragma unroll
      for (int i = 0; i < 12; ++i){
        float4 w = w1[64*i], x = zl[64*i];
        acc = fmaf(w.x,x.x, fmaf(w.y,x.y, fmaf(w.z,x.z, fmaf(w.w,x.w, acc))));
      }
      acc += __shfl_xor(acc,32); acc += __shfl_xor(acc,16); acc += __shfl_xor(acc,8);
      acc += __shfl_xor(acc,4);  acc += __shfl_xor(acc,2);  acc += __shfl_xor(acc,1);
      hb ^= 1;
      if (lane == 0) st1(&g_h[hb][row1], softplus_f(acc + b1));
    }
    publish(); poll_all(); load_h();
    // ---- 3 hidden layers ----
    #pragma unroll
    for (int l = 0; l < 3; ++l){
      const float4* wr = (l==0) ? wh0 : (l==1) ? wh1 : wh2;
      const float bh  = (l==0) ? bh0 : (l==1) ? bh1 : bh2;
      const float4* hx = reinterpret_cast<const float4*>(hsh) + lane;
      float acc = 0.f;
      #pragma unroll
      for (int i = 0; i < 3; ++i){
        float4 w = wr[64*i], x = hx[64*i];
        acc = fmaf(w.x,x.x, fmaf(w.y,x.y, fmaf(w.z,x.z, fmaf(w.w,x.w, acc))));
      }
      acc += __shfl_xor(acc,32); acc += __shfl_xor(acc,16); acc += __shfl_xor(acc,8);
      acc += __shfl_xor(acc,4);  acc += __shfl_xor(acc,2);  acc += __shfl_xor(acc,1);
      hb ^= 1;
      if (lane == 0) st1(&g_h[hb][row1], softplus_f(acc + bh));
      publish(); poll_all(); load_h();
    }
    // ---- out layer: 3072x768, 16 lanes/row; k-slice block-local ----
    {
      const float4* hx = reinterpret_cast<const float4*>(hsh) + l16;
      float acc = 0.f;
      #pragma unroll
      for (int i = 0; i < 12; ++i){
        float4 w = wo[16*i], x = hx[16*i];
        acc = fmaf(w.x,x.x, fmaf(w.y,x.y, fmaf(w.z,x.z, fmaf(w.w,x.w, acc))));
      }
      acc += __shfl_xor(acc,8); acc += __shfl_xor(acc,4);
      acc += __shfl_xor(acc,2); acc += __shfl_xor(acc,1);
      if (l16 == 0) kc[kslot(st+1)][ro] = acc + bo;
    }
    __syncthreads();
    // ---- local folding ----
    if (st >= 1 && st <= 5){
      if (tid < 16){
        float s = 0.f;
        for (int j = 1; j <= st+1; ++j) s += d_AT[st+1][j-1] * kc[kslot(j)][tid];
        const float zv = ysl[tid] + dte * s;
        st1(&g_z[blk*16 + tid], zv);
        if (st == 5) y1sl[tid] = zv;
      }
      publish();                       // consumed at next feval's z-acquire
    }
    if (st == 6){
      if (tid < 16){
        float ev = 0.f;
        for (int j = 1; j <= 7; ++j) ev += d_EC[j-1] * kc[kslot(j)][tid];
        ev *= dte;
        const float sc = 1e-6f + 1e-3f * fmaxf(fabsf(ysl[tid]), fabsf(y1sl[tid]));
        const float q = ev / sc;
        float v = q*q;
        v += __shfl_xor(v,8); v += __shfl_xor(v,4); v += __shfl_xor(v,2); v += __shfl_xor(v,1);
        if (tid == 0) st1(&g_p[blk], v);
      }
      publish();                       // consumed by err reduce
    }
  };

  // k1 = f(y0) once; FSAL-carried afterwards
  feval(0, 0.f);

  float t = 0.f, dtv = 0.1f;
  for (int iv = 1; iv < 100; ++iv){
    const float t1 = (float)iv / 99.0f;
    for (int a = 0; a < 6; ++a){
      if (t >= t1 - 1e-10f) break;
      if (tid == 0) s_ab = abort_now();
      __syncthreads();
      if (s_ab) return;                // fail fast, never wedge
      const float dte = fminf(dtv, t1 - t);

      // z for stage 2 (block-local k1 slice)
      if (tid < 16)
        st1(&g_z[blk*16 + tid], ysl[tid] + dte * 0.161f * kc[kslot(1)][tid]);
      publish();

      feval(1,dte); feval(2,dte); feval(3,dte);
      feval(4,dte); feval(5,dte); feval(6,dte);

      // err: gather 192 partials once, deterministic fixed-order reduce
      poll_all();
      float v = 0.f;
      if (tid < NBLK) v = ld1(&g_p[tid]);
      v += __shfl_xor(v,32); v += __shfl_xor(v,16); v += __shfl_xor(v,8);
      v += __shfl_xor(v,4);  v += __shfl_xor(v,2);  v += __shfl_xor(v,1);
      if (lane == 0) red[wave] = v;
      __syncthreads();
      const float err = sqrtf((red[0]+red[1]+red[2]+red[3]) * (1.0f/3072.0f));
      __syncthreads();

      const bool accept = (err <= 1.0f);
      const float factor = fminf(fmaxf(0.9f * powf(fmaxf(err, 1e-10f), -0.2f), 0.2f), 10.0f);
      if (accept){
        t += dte;
        if (tid < 16) ysl[tid] = y1sl[tid];
        kpar ^= 1;
      }
      dtv = dte * factor;
      __syncthreads();
    }
    t = t1;
    // y-publish phase: owners expose accepted y; emitters read their 8 words
    if (tid < 16) st1(&g_ypub[blk*16 + tid], ysl[tid]);
    publish(); poll_all();
    if (tid < 4){
      const int e = blk*4 + tid;
      const float m = ld1(&g_ypub[e]);
      const float s = ld1(&g_ypub[HID + e]);
      out[(size_t)iv*HID + e] = m + eps[(size_t)iv*HID + e]*s;
    }
  }
}

extern "C" void kernel_launch(void* const* d_in, const int* in_sizes, int n_in,
                              void* d_out, int out_size, void* d_ws, size_t ws_size,
                              hipStream_t stream) {
  const float* y0   = (const float*)d_in[0];
  const float* Win  = (const float*)d_in[1];
  const float* bin  = (const float*)d_in[2];
  const float* Whid = (const float*)d_in[3];
  const float* bhid = (const float*)d_in[4];
  const float* Wout = (const float*)d_in[5];
  const float* bout = (const float*)d_in[6];
  const float* eps  = (const float*)d_in[7];
  float* out = (float*)d_out;
  (void)in_sizes; (void)n_in; (void)out_size; (void)d_ws; (void)ws_size;

  reset_kernel<<<dim3(1), dim3(BLK), 0, stream>>>();
  ode_kernel<<<dim3(NBLK), dim3(BLK), 0, stream>>>(y0, Win, bin, Whid, bhid, Wout, bout, eps, out);
}